// Round 6
// baseline (232.868 us; speedup 1.0000x reference)
//
#include <hip/hip_runtime.h>
#include <math.h>

// Problem constants
#define NB   16
#define NN   512
#define FIN  256
#define HID  128
#define FOUT 256
#define TOPK 16
#define ROWS (NB*NN)
#define LN_EPS 1e-5f

// MFMA tiling: 64x64 block tile, BK=32
#define BK  32
#define LDK 40   // padded LDS row (ushort): 80 B stride, 16B-aligned frags

typedef __attribute__((ext_vector_type(8)))  short  bf16x8;
typedef __attribute__((ext_vector_type(4)))  float  f32x4;
typedef __attribute__((ext_vector_type(8)))  unsigned short u16x8;

#define MFMA3(d, ah, al, bh, bl)                                              \
    d = __builtin_amdgcn_mfma_f32_16x16x32_bf16(ah, bh, d, 0, 0, 0);          \
    d = __builtin_amdgcn_mfma_f32_16x16x32_bf16(ah, bl, d, 0, 0, 0);          \
    d = __builtin_amdgcn_mfma_f32_16x16x32_bf16(al, bh, d, 0, 0, 0);

// fp32 -> (hi, lo) bf16 split.  x = hi + lo + O(2^-18 |x|)
__device__ __forceinline__ ushort f2bf_rn(float x) {
    uint u = __float_as_uint(x);
    u += 0x7fff + ((u >> 16) & 1);
    return (ushort)(u >> 16);
}
__device__ __forceinline__ float bf2f(ushort h) {
    return __uint_as_float(((uint)h) << 16);
}
__device__ __forceinline__ void split2(float x, ushort& hi, ushort& lo) {
    hi = f2bf_rn(x);
    lo = f2bf_rn(x - bf2f(hi));
}

// stage 64 rows x 32 k of a pre-split ushort plane into LDS (pure copy)
__device__ __forceinline__ void stage_u(ushort (*Ds)[LDK], const ushort* __restrict__ src,
                                        int rstride, int tid)
{
    const int r = tid >> 2, seg = (tid & 3) * 8;
    *(u16x8*)&Ds[r][seg] = *(const u16x8*)(src + (size_t)r * rstride + seg);
}

// one BK=32 step: 2x2 16x16 tiles per wave, 3 MFMAs per tile (split product)
__device__ __forceinline__ void mma_step64(const ushort (*Ah)[LDK], const ushort (*Al)[LDK],
                                           const ushort (*Bh)[LDK], const ushort (*Bl)[LDK],
                                           f32x4 acc[2][2], int wr, int wc, int lane)
{
    const int q8 = (lane >> 4) * 8, m = lane & 15;
    bf16x8 ah[2], al[2], bh[2], bl[2];
    #pragma unroll
    for (int i = 0; i < 2; i++) {
        ah[i] = *(const bf16x8*)&Ah[wr + 16*i + m][q8];
        al[i] = *(const bf16x8*)&Al[wr + 16*i + m][q8];
        bh[i] = *(const bf16x8*)&Bh[wc + 16*i + m][q8];
        bl[i] = *(const bf16x8*)&Bl[wc + 16*i + m][q8];
    }
    #pragma unroll
    for (int i = 0; i < 2; i++)
        #pragma unroll
        for (int j = 0; j < 2; j++) {
            MFMA3(acc[i][j], ah[i], al[i], bh[j], bl[j]);
        }
}

#define MM64_PROLOGUE()                                                     \
    __shared__ ushort smem[4*64*LDK];                                       \
    ushort (*Ah)[LDK] = (ushort (*)[LDK])(smem);                            \
    ushort (*Al)[LDK] = (ushort (*)[LDK])(smem + 64*LDK);                   \
    ushort (*Bh)[LDK] = (ushort (*)[LDK])(smem + 2*64*LDK);                 \
    ushort (*Bl)[LDK] = (ushort (*)[LDK])(smem + 3*64*LDK);                 \
    float* fbuf = (float*)smem;  /* epilogue reuse */                       \
    const int tid = threadIdx.x, lane = tid & 63, wv = tid >> 6;            \
    const int wr = (wv >> 1) * 32, wc = (wv & 1) * 32;                      \
    f32x4 acc[2][2];                                                        \
    _Pragma("unroll")                                                       \
    for (int i = 0; i < 2; i++)                                             \
        _Pragma("unroll")                                                   \
        for (int j = 0; j < 2; j++)                                         \
            acc[i][j] = (f32x4){0.f, 0.f, 0.f, 0.f};

// ---------------------------------------------------------------------------
// P0: merged prep: weights (blk<8: Wt, blk<16: Wct, blk==16: biases),
//     blk>=17: X hi/lo split
// ---------------------------------------------------------------------------
__global__ __launch_bounds__(256) void k_prep(
    const float* __restrict__ Wq, const float* __restrict__ Wk,
    const float* __restrict__ Wv, const float* __restrict__ Wr,
    const float* __restrict__ Wc,
    const float* __restrict__ bq, const float* __restrict__ bk,
    const float* __restrict__ bv, const float* __restrict__ br,
    const float* __restrict__ bc,
    const float* __restrict__ X,
    ushort* __restrict__ Wth, ushort* __restrict__ Wtl,
    ushort* __restrict__ Wcth, ushort* __restrict__ Wctl,
    float* __restrict__ bcat, float* __restrict__ bcab,
    ushort* __restrict__ Xh, ushort* __restrict__ Xl)
{
    const int blk = blockIdx.x, tid = threadIdx.x;
    __shared__ float fb[64][65];

    if (blk >= 17) {                     // X split
        const size_t base = ((size_t)(blk - 17) * 256 + tid) * 8;
        const float4 a = *(const float4*)(X + base);
        const float4 b = *(const float4*)(X + base + 4);
        u16x8 vh, vl; ushort hh, ll;
        split2(a.x,hh,ll); vh[0]=hh; vl[0]=ll;
        split2(a.y,hh,ll); vh[1]=hh; vl[1]=ll;
        split2(a.z,hh,ll); vh[2]=hh; vl[2]=ll;
        split2(a.w,hh,ll); vh[3]=hh; vl[3]=ll;
        split2(b.x,hh,ll); vh[4]=hh; vl[4]=ll;
        split2(b.y,hh,ll); vh[5]=hh; vl[5]=ll;
        split2(b.z,hh,ll); vh[6]=hh; vl[6]=ll;
        split2(b.w,hh,ll); vh[7]=hh; vl[7]=ll;
        *(u16x8*)(Xh + base) = vh;
        *(u16x8*)(Xl + base) = vl;
        return;
    }

    if (blk < 8) {                       // Wt tiles: n0 = blk*64
        const int n0 = blk * 64;
        const int widx = n0 >> 7;
        const float* W = widx==0 ? Wq : widx==1 ? Wk : widx==2 ? Wv : Wr;
        const int cbase = n0 & 127;
        for (int kt = 0; kt < 4; kt++) {
            const int k0 = kt * 64;
            __syncthreads();
            {
                const int kk = tid >> 2, cs = (tid & 3) * 16;
                #pragma unroll
                for (int t = 0; t < 16; t += 4) {
                    const float4 q = *(const float4*)&W[(size_t)(k0+kk)*HID + cbase + cs + t];
                    fb[kk][cs+t]=q.x; fb[kk][cs+t+1]=q.y; fb[kk][cs+t+2]=q.z; fb[kk][cs+t+3]=q.w;
                }
            }
            __syncthreads();
            {
                const int c = tid >> 2, ks = (tid & 3) * 16;
                u16x8 vh0, vh1, vl0, vl1;
                #pragma unroll
                for (int t = 0; t < 8; t++) {
                    ushort hh, ll;
                    split2(fb[ks+t][c], hh, ll); vh0[t]=hh; vl0[t]=ll;
                    split2(fb[ks+8+t][c], hh, ll); vh1[t]=hh; vl1[t]=ll;
                }
                *(u16x8*)&Wth[(size_t)(n0+c)*256 + k0 + ks]     = vh0;
                *(u16x8*)&Wth[(size_t)(n0+c)*256 + k0 + ks + 8] = vh1;
                *(u16x8*)&Wtl[(size_t)(n0+c)*256 + k0 + ks]     = vl0;
                *(u16x8*)&Wtl[(size_t)(n0+c)*256 + k0 + ks + 8] = vl1;
            }
        }
    } else if (blk < 16) {               // Wct tiles: n0 = (blk-8)*64
        const int n0 = (blk - 8) * 64;
        const bool ahalf = n0 < 256;
        const int cbase = n0 & 255;
        for (int kt = 0; kt < 2; kt++) {
            const int k0 = kt * 64;
            __syncthreads();
            {
                const int kk = tid >> 2, cs = (tid & 3) * 16;
                #pragma unroll
                for (int t = 0; t < 16; t++) {
                    const float bot = Wc[(size_t)(HID + k0 + kk)*FOUT + cbase + cs + t];
                    float val = bot;
                    if (ahalf) val = Wc[(size_t)(k0 + kk)*FOUT + cbase + cs + t] - bot;
                    fb[kk][cs+t] = val;
                }
            }
            __syncthreads();
            {
                const int c = tid >> 2, ks = (tid & 3) * 16;
                u16x8 vh0, vh1, vl0, vl1;
                #pragma unroll
                for (int t = 0; t < 8; t++) {
                    ushort hh, ll;
                    split2(fb[ks+t][c], hh, ll); vh0[t]=hh; vl0[t]=ll;
                    split2(fb[ks+8+t][c], hh, ll); vh1[t]=hh; vl1[t]=ll;
                }
                *(u16x8*)&Wcth[(size_t)(n0+c)*128 + k0 + ks]     = vh0;
                *(u16x8*)&Wcth[(size_t)(n0+c)*128 + k0 + ks + 8] = vh1;
                *(u16x8*)&Wctl[(size_t)(n0+c)*128 + k0 + ks]     = vl0;
                *(u16x8*)&Wctl[(size_t)(n0+c)*128 + k0 + ks + 8] = vl1;
            }
        }
    } else {                             // scalars
        for (int i = tid; i < 512; i += 256) {
            const int w = i >> 7, c = i & 127;
            bcat[i] = w==0 ? bq[c] : w==1 ? bk[c] : w==2 ? bv[c] : br[c];
            bcab[i] = i < 256 ? bc[i] : 0.f;
        }
    }
}

// ---------------------------------------------------------------------------
// K1: projection GEMM. ct 0..3 -> q|k planes [8192][256]; ct 4,5 -> V
//     transposed planes [b][128][512]; ct 6,7 -> R fp32 [8192][128].
// ---------------------------------------------------------------------------
__global__ __launch_bounds__(256) void k_proj_m(
    const ushort* __restrict__ Xh, const ushort* __restrict__ Xl,
    const ushort* __restrict__ Wth, const ushort* __restrict__ Wtl,
    const float* __restrict__ bcat,
    ushort* __restrict__ Yh, ushort* __restrict__ Yl,
    ushort* __restrict__ Vth, ushort* __restrict__ Vtl,
    float* __restrict__ Rbuf)
{
    const int ct  = blockIdx.x;          // 64-col tile of Wcat (0..7)
    const int br0 = blockIdx.y * 64;     // global row

    MM64_PROLOGUE();

    for (int k0 = 0; k0 < FIN; k0 += BK) {
        stage_u(Ah, Xh + (size_t)br0 * 256 + k0, 256, tid);
        stage_u(Al, Xl + (size_t)br0 * 256 + k0, 256, tid);
        stage_u(Bh, Wth + (size_t)(ct*64) * 256 + k0, 256, tid);
        stage_u(Bl, Wtl + (size_t)(ct*64) * 256 + k0, 256, tid);
        __syncthreads();
        mma_step64(Ah, Al, Bh, Bl, acc, wr, wc, lane);
        __syncthreads();
    }

    // write acc + bias into fbuf[64][65]
    {
        const int m = lane & 15, q4 = (lane >> 4) * 4;
        #pragma unroll
        for (int i = 0; i < 2; i++)
            #pragma unroll
            for (int reg = 0; reg < 4; reg++) {
                const int r = wr + 16*i + q4 + reg;
                #pragma unroll
                for (int j = 0; j < 2; j++) {
                    const int c = wc + 16*j + m;
                    fbuf[r*65 + c] = acc[i][j][reg] + bcat[ct*64 + c];
                }
            }
    }
    __syncthreads();

    if (ct < 4) {            // q|k planes, row-major
        const int r = tid >> 2, cs = (tid & 3) * 16;
        u16x8 vh0, vh1, vl0, vl1;
        #pragma unroll
        for (int t = 0; t < 8; t++) {
            ushort hh, ll;
            split2(fbuf[r*65 + cs + t], hh, ll);     vh0[t]=hh; vl0[t]=ll;
            split2(fbuf[r*65 + cs + 8 + t], hh, ll); vh1[t]=hh; vl1[t]=ll;
        }
        const size_t o = (size_t)(br0 + r) * 256 + ct*64 + cs;
        *(u16x8*)&Yh[o]   = vh0; *(u16x8*)&Yh[o+8] = vh1;
        *(u16x8*)&Yl[o]   = vl0; *(u16x8*)&Yl[o+8] = vl1;
    } else if (ct < 6) {     // V transposed planes
        const int cl = tid >> 2, rs = (tid & 3) * 16;
        const int b = br0 >> 9, nb = br0 & 511;
        const int cglob = (ct - 4) * 64 + cl;
        u16x8 vh0, vh1, vl0, vl1;
        #pragma unroll
        for (int t = 0; t < 8; t++) {
            ushort hh, ll;
            split2(fbuf[(rs+t)*65 + cl], hh, ll);   vh0[t]=hh; vl0[t]=ll;
            split2(fbuf[(rs+8+t)*65 + cl], hh, ll); vh1[t]=hh; vl1[t]=ll;
        }
        const size_t o = ((size_t)b*128 + cglob) * 512 + nb + rs;
        *(u16x8*)&Vth[o]   = vh0; *(u16x8*)&Vth[o+8] = vh1;
        *(u16x8*)&Vtl[o]   = vl0; *(u16x8*)&Vtl[o+8] = vl1;
    } else {                 // R fp32 [8192][128]
        const int r = tid >> 2, cs = (tid & 3) * 16;
        float* dst = Rbuf + (size_t)(br0 + r) * 128 + (ct - 6)*64 + cs;
        #pragma unroll
        for (int t = 0; t < 16; t += 4) {
            float4 q;
            q.x = fbuf[r*65+cs+t];   q.y = fbuf[r*65+cs+t+1];
            q.z = fbuf[r*65+cs+t+2]; q.w = fbuf[r*65+cs+t+3];
            *(float4*)(dst + t) = q;
        }
    }
}

// ---------------------------------------------------------------------------
// K2: fused flash attention: S=QK^T/sqrt -> online softmax -> O=PV; h=O/l+R
//     One wave owns 16 Q rows, all 64 m-cols per tile; no barriers.
//     Writes split H planes + SQ.
// ---------------------------------------------------------------------------
__global__ __launch_bounds__(128) void k_attn(
    const ushort* __restrict__ Yh, const ushort* __restrict__ Yl,
    const ushort* __restrict__ Vth, const ushort* __restrict__ Vtl,
    const float* __restrict__ Rbuf,
    ushort* __restrict__ Hh, ushort* __restrict__ Hl,
    float* __restrict__ SQ)
{
    const int wv = threadIdx.x >> 6, lane = threadIdx.x & 63;
    const int b  = blockIdx.x >> 4;                    // 16 blocks per batch
    const int n0 = (blockIdx.x & 15) * 32 + wv * 16;   // wave's 16-row base
    const int L = lane & 15, quad = lane >> 4;
    const int grow0 = b * NN + n0;
    const float scale = 0.08838834764831845f;

    __shared__ ushort Pb[2][2][16][68];   // [wave][plane][row][col(+pad)]
    ushort (*Pbh)[68] = Pb[wv][0];
    ushort (*Pbl)[68] = Pb[wv][1];

    // Q A-frags (resident): 4 BK-steps, hi/lo
    bf16x8 qh[4], ql[4];
    {
        const ushort* q1 = Yh + (size_t)(grow0 + L) * 256 + quad * 8;
        const ushort* q2 = Yl + (size_t)(grow0 + L) * 256 + quad * 8;
        #pragma unroll
        for (int s = 0; s < 4; s++) {
            qh[s] = *(const bf16x8*)(q1 + 32*s);
            ql[s] = *(const bf16x8*)(q2 + 32*s);
        }
    }

    f32x4 O[8];
    #pragma unroll
    for (int j = 0; j < 8; j++) O[j] = (f32x4){0.f,0.f,0.f,0.f};
    float m_i[4] = {-INFINITY,-INFINITY,-INFINITY,-INFINITY};
    float l_i[4] = {0.f,0.f,0.f,0.f};

    for (int m0 = 0; m0 < NN; m0 += 64) {
        // ---- S tile: 16 x 64 (4 j-frags) ----
        f32x4 Sf[4];
        #pragma unroll
        for (int j = 0; j < 4; j++) Sf[j] = (f32x4){0.f,0.f,0.f,0.f};
        #pragma unroll
        for (int s = 0; s < 4; s++) {
            #pragma unroll
            for (int j = 0; j < 4; j++) {
                const size_t ko = (size_t)(b*NN + m0 + 16*j + L) * 256 + 128 + 32*s + quad*8;
                bf16x8 kh = *(const bf16x8*)(Yh + ko);
                bf16x8 kl = *(const bf16x8*)(Yl + ko);
                MFMA3(Sf[j], qh[s], ql[s], kh, kl);
            }
        }
        #pragma unroll
        for (int j = 0; j < 4; j++)
            #pragma unroll
            for (int r = 0; r < 4; r++) Sf[j][r] *= scale;

        // ---- online softmax stats (rows live in 16-lane groups) ----
        float nm[4], al[4];
        #pragma unroll
        for (int r = 0; r < 4; r++) {
            float mx = fmaxf(fmaxf(Sf[0][r], Sf[1][r]), fmaxf(Sf[2][r], Sf[3][r]));
            mx = fmaxf(mx, __shfl_xor(mx, 1));
            mx = fmaxf(mx, __shfl_xor(mx, 2));
            mx = fmaxf(mx, __shfl_xor(mx, 4));
            mx = fmaxf(mx, __shfl_xor(mx, 8));
            nm[r] = fmaxf(m_i[r], mx);
            al[r] = __expf(m_i[r] - nm[r]);
            m_i[r] = nm[r];
        }
        float rs[4] = {0.f,0.f,0.f,0.f};
        #pragma unroll
        for (int j = 0; j < 4; j++) {
            #pragma unroll
            for (int r = 0; r < 4; r++) {
                const float p = __expf(Sf[j][r] - nm[r]);
                rs[r] += p;
                ushort hh, ll; split2(p, hh, ll);
                Pbh[quad*4 + r][16*j + L] = hh;
                Pbl[quad*4 + r][16*j + L] = ll;
            }
        }
        #pragma unroll
        for (int r = 0; r < 4; r++) {
            float s2 = rs[r];
            s2 += __shfl_xor(s2, 1); s2 += __shfl_xor(s2, 2);
            s2 += __shfl_xor(s2, 4); s2 += __shfl_xor(s2, 8);
            l_i[r] = l_i[r] * al[r] + s2;
        }
        // ---- rescale O ----
        #pragma unroll
        for (int j = 0; j < 8; j++)
            #pragma unroll
            for (int r = 0; r < 4; r++) O[j][r] *= al[r];

        // ---- O += P @ V  (K = 64, two BK steps) ----
        #pragma unroll
        for (int s = 0; s < 2; s++) {
            bf16x8 ph = *(const bf16x8*)&Pbh[L][32*s + quad*8];
            bf16x8 pl = *(const bf16x8*)&Pbl[L][32*s + quad*8];
            #pragma unroll
            for (int j = 0; j < 8; j++) {
                const size_t vo = ((size_t)(b*128 + 16*j + L)) * 512 + m0 + 32*s + quad*8;
                bf16x8 vh = *(const bf16x8*)(Vth + vo);
                bf16x8 vl = *(const bf16x8*)(Vtl + vo);
                MFMA3(O[j], ph, pl, vh, vl);
            }
        }
    }

    // ---- epilogue: h = O/l + R; SQ; split H planes ----
    #pragma unroll
    for (int r = 0; r < 4; r++) {
        const int grow = grow0 + quad*4 + r;
        const float invl = 1.0f / l_i[r];
        float sq = 0.f;
        #pragma unroll
        for (int j = 0; j < 8; j++) {
            const int c = 16*j + L;
            const float h = O[j][r] * invl + Rbuf[(size_t)grow*128 + c];
            sq += h*h;
            ushort hh, ll; split2(h, hh, ll);
            Hh[(size_t)grow*128 + c] = hh;
            Hl[(size_t)grow*128 + c] = ll;
        }
        sq += __shfl_xor(sq, 1); sq += __shfl_xor(sq, 2);
        sq += __shfl_xor(sq, 4); sq += __shfl_xor(sq, 8);
        if (L == 0) SQ[grow] = sq;
    }
}

// ---------------------------------------------------------------------------
// K3: AB[8192,512] fp32: a-half = h@(Wc_top-Wc_bot)+bc, b-half = h@Wc_bot
// ---------------------------------------------------------------------------
__global__ __launch_bounds__(256) void k_ab_m(
    const ushort* __restrict__ Hh, const ushort* __restrict__ Hl,
    const ushort* __restrict__ Wcth, const ushort* __restrict__ Wctl,
    const float* __restrict__ bcab, float* __restrict__ AB)
{
    const int ct  = blockIdx.x;            // 0..7
    const int br0 = blockIdx.y * 64;

    MM64_PROLOGUE();

    for (int k0 = 0; k0 < HID; k0 += BK) {
        stage_u(Ah, Hh + (size_t)br0 * 128 + k0, 128, tid);
        stage_u(Al, Hl + (size_t)br0 * 128 + k0, 128, tid);
        stage_u(Bh, Wcth + (size_t)(ct*64) * 128 + k0, 128, tid);
        stage_u(Bl, Wctl + (size_t)(ct*64) * 128 + k0, 128, tid);
        __syncthreads();
        mma_step64(Ah, Al, Bh, Bl, acc, wr, wc, lane);
        __syncthreads();
    }

    const int m = lane & 15, q4 = (lane >> 4) * 4;
    #pragma unroll
    for (int i = 0; i < 2; i++)
        #pragma unroll
        for (int reg = 0; reg < 4; reg++) {
            const int grow = br0 + wr + 16*i + q4 + reg;
            #pragma unroll
            for (int j = 0; j < 2; j++) {
                const int c = wc + 16*j + m;
                AB[(size_t)grow * 512 + ct*64 + c] = acc[i][j][reg] + bcab[ct*64 + c];
            }
        }
}

// ---------------------------------------------------------------------------
// K4: D[b,n,m] = SQ[n] + SQ[m] - 2 (h_n . h_m)
// ---------------------------------------------------------------------------
__global__ __launch_bounds__(256) void k_dist_m(
    const ushort* __restrict__ Hh, const ushort* __restrict__ Hl,
    const float* __restrict__ SQ, float* __restrict__ D)
{
    const int b = blockIdx.z;
    const int m0 = blockIdx.x * 64, n0 = blockIdx.y * 64;

    MM64_PROLOGUE();

    for (int k0 = 0; k0 < HID; k0 += BK) {
        stage_u(Ah, Hh + (size_t)(b*NN + n0) * 128 + k0, 128, tid);
        stage_u(Al, Hl + (size_t)(b*NN + n0) * 128 + k0, 128, tid);
        stage_u(Bh, Hh + (size_t)(b*NN + m0) * 128 + k0, 128, tid);
        stage_u(Bl, Hl + (size_t)(b*NN + m0) * 128 + k0, 128, tid);
        __syncthreads();
        mma_step64(Ah, Al, Bh, Bl, acc, wr, wc, lane);
        __syncthreads();
    }

    const int gb = b * NN;
    float* Db = D + (size_t)b * NN * NN;
    const int m = lane & 15, q4 = (lane >> 4) * 4;
    float sqm[2];
    #pragma unroll
    for (int j = 0; j < 2; j++) sqm[j] = SQ[gb + m0 + wc + 16*j + m];
    #pragma unroll
    for (int i = 0; i < 2; i++)
        #pragma unroll
        for (int reg = 0; reg < 4; reg++) {
            const int n = n0 + wr + 16*i + q4 + reg;
            const float sqn = SQ[gb + n];
            #pragma unroll
            for (int j = 0; j < 2; j++)
                Db[(size_t)n * NN + m0 + wc + 16*j + m]
                    = sqn + sqm[j] - 2.0f * acc[i][j][reg];
        }
}

// ---------------------------------------------------------------------------
// K5: per-row top-16 + gather-max + LayerNorm + SELU (wave per row)
// ---------------------------------------------------------------------------
__global__ __launch_bounds__(256) void k_out(
    const float* __restrict__ D, const float* __restrict__ AB,
    const float* __restrict__ ln_scale, const float* __restrict__ ln_bias,
    float* __restrict__ out)
{
    const int row  = blockIdx.x * 4 + (threadIdx.x >> 6);
    const int lane = threadIdx.x & 63;
    const int gb0  = row & ~(NN - 1);

    const float* drow = D + (size_t)row * NN;
    const float4 q0 = ((const float4*)drow)[lane];
    const float4 q1 = ((const float4*)drow)[64 + lane];
    float v[8] = {q0.x, q0.y, q0.z, q0.w, q1.x, q1.y, q1.z, q1.w};

    const float lsc0 = ln_scale[lane],       lbi0 = ln_bias[lane];
    const float lsc1 = ln_scale[lane + 64],  lbi1 = ln_bias[lane + 64];
    const float lsc2 = ln_scale[lane + 128], lbi2 = ln_bias[lane + 128];
    const float lsc3 = ln_scale[lane + 192], lbi3 = ln_bias[lane + 192];
    const float* arow = AB + (size_t)row * 512;
    const float a0 = arow[lane], a1 = arow[lane + 64],
                a2 = arow[lane + 128], a3 = arow[lane + 192];

    float bm0 = -INFINITY, bm1 = -INFINITY, bm2 = -INFINITY, bm3 = -INFINITY;

    for (int it = 0; it < TOPK; it++) {
        float bestv = v[0]; int bestm = 4*lane;
        #pragma unroll
        for (int j = 1; j < 8; j++) {
            const int m = (j >> 2)*256 + 4*lane + (j & 3);
            if (v[j] < bestv) { bestv = v[j]; bestm = m; }
        }
        #pragma unroll
        for (int off = 1; off < 64; off <<= 1) {
            const float ov = __shfl_xor(bestv, off);
            const int   om = __shfl_xor(bestm, off);
            if (ov < bestv || (ov == bestv && om < bestm)) { bestv = ov; bestm = om; }
        }
        const float* brow = AB + (size_t)(gb0 + bestm) * 512 + 256;
        bm0 = fmaxf(bm0, brow[lane]);
        bm1 = fmaxf(bm1, brow[lane + 64]);
        bm2 = fmaxf(bm2, brow[lane + 128]);
        bm3 = fmaxf(bm3, brow[lane + 192]);
        if (((bestm >> 2) & 63) == lane) {
            const int jj = ((bestm >> 8) << 2) | (bestm & 3);
            #pragma unroll
            for (int j = 0; j < 8; j++) if (j == jj) v[j] = INFINITY;
        }
    }

    float y0 = a0 + bm0, y1 = a1 + bm1, y2 = a2 + bm2, y3 = a3 + bm3;

    float s = y0 + y1 + y2 + y3;
    #pragma unroll
    for (int off = 1; off < 64; off <<= 1) s += __shfl_xor(s, off);
    const float mu = s * (1.0f/256.0f);
    const float d0 = y0 - mu, d1 = y1 - mu, d2 = y2 - mu, d3 = y3 - mu;
    float s2 = d0*d0 + d1*d1 + d2*d2 + d3*d3;
    #pragma unroll
    for (int off = 1; off < 64; off <<= 1) s2 += __shfl_xor(s2, off);
    const float var = s2 * (1.0f/256.0f);
    const float rstd = rsqrtf(var + LN_EPS);

    const float lam = 1.0507009873554805f, alpha = 1.6732632423543772f;
    float* orow = out + (size_t)row * FOUT;
    { const float z = d0*rstd*lsc0 + lbi0; orow[lane]       = z > 0.f ? lam*z : lam*alpha*expm1f(z); }
    { const float z = d1*rstd*lsc1 + lbi1; orow[lane + 64]  = z > 0.f ? lam*z : lam*alpha*expm1f(z); }
    { const float z = d2*rstd*lsc2 + lbi2; orow[lane + 128] = z > 0.f ? lam*z : lam*alpha*expm1f(z); }
    { const float z = d3*rstd*lsc3 + lbi3; orow[lane + 192] = z > 0.f ? lam*z : lam*alpha*expm1f(z); }
}

// ---------------------------------------------------------------------------
extern "C" void kernel_launch(void* const* d_in, const int* in_sizes, int n_in,
                              void* d_out, int out_size, void* d_ws, size_t ws_size,
                              hipStream_t stream)
{
    (void)in_sizes; (void)n_in; (void)out_size; (void)ws_size;
    const float* X   = (const float*)d_in[0];
    const float* Wq  = (const float*)d_in[2];
    const float* bq  = (const float*)d_in[3];
    const float* Wk  = (const float*)d_in[4];
    const float* bk  = (const float*)d_in[5];
    const float* Wv  = (const float*)d_in[6];
    const float* bv  = (const float*)d_in[7];
    const float* Wr  = (const float*)d_in[8];
    const float* br  = (const float*)d_in[9];
    const float* Wc  = (const float*)d_in[10];
    const float* bc  = (const float*)d_in[11];
    const float* lns = (const float*)d_in[12];
    const float* lnb = (const float*)d_in[13];
    float* out = (float*)d_out;

    char* cur = (char*)d_ws;
    auto alloc = [&](size_t bytes) { char* p = cur; cur += (bytes + 255) & ~size_t(255); return p; };

    float*  Dst  = (float*)alloc((size_t)NB*NN*NN*4);     // D (dist)
    float*  AB   = (float*)alloc((size_t)ROWS*512*4);
    float*  Rbuf = (float*)alloc((size_t)ROWS*128*4);
    float*  SQ   = (float*)alloc((size_t)ROWS*4);
    float*  bcat = (float*)alloc(512*4);
    float*  bcab = (float*)alloc(512*4);
    ushort* Xh   = (ushort*)alloc((size_t)ROWS*256*2);
    ushort* Xl   = (ushort*)alloc((size_t)ROWS*256*2);
    ushort* Yh   = (ushort*)alloc((size_t)ROWS*256*2);    // q|k planes
    ushort* Yl   = (ushort*)alloc((size_t)ROWS*256*2);
    ushort* Vth  = (ushort*)alloc((size_t)NB*128*512*2);
    ushort* Vtl  = (ushort*)alloc((size_t)NB*128*512*2);
    ushort* Hh   = (ushort*)alloc((size_t)ROWS*128*2);
    ushort* Hl   = (ushort*)alloc((size_t)ROWS*128*2);
    ushort* Wth  = (ushort*)alloc((size_t)512*256*2);
    ushort* Wtl  = (ushort*)alloc((size_t)512*256*2);
    ushort* Wcth = (ushort*)alloc((size_t)512*128*2);
    ushort* Wctl = (ushort*)alloc((size_t)512*128*2);

    k_prep   <<<17 + ROWS*256/(256*8), 256, 0, stream>>>(
                 Wq,Wk,Wv,Wr,Wc, bq,bk,bv,br,bc, X,
                 Wth,Wtl,Wcth,Wctl, bcat,bcab, Xh,Xl);
    k_proj_m <<<dim3(8,128),  256, 0, stream>>>(Xh,Xl, Wth,Wtl, bcat, Yh,Yl, Vth,Vtl, Rbuf);
    k_attn   <<<NB*16,        128, 0, stream>>>(Yh,Yl, Vth,Vtl, Rbuf, Hh,Hl, SQ);
    k_ab_m   <<<dim3(8,128),  256, 0, stream>>>(Hh,Hl, Wcth,Wctl, bcab, AB);
    k_dist_m <<<dim3(8,8,16), 256, 0, stream>>>(Hh,Hl, SQ, Dst);
    k_out    <<<ROWS/4,       256, 0, stream>>>(Dst, AB, lns, lnb, out);
}